// Round 1
// 282.570 us; speedup vs baseline: 1.0531x; 1.0531x over previous
//
#include <hip/hip_runtime.h>
#include <cstdint>
#include <cstddef>

// FP32 in/out. Compute: fp32 -> bf16 -> MFMA (fp32 acc) -> fp32 out.
typedef unsigned short u16;
typedef __attribute__((ext_vector_type(8))) __bf16 bf16x8;
typedef __attribute__((ext_vector_type(8))) unsigned short u16x8;
typedef __attribute__((ext_vector_type(4))) unsigned short u16x4;
typedef __attribute__((ext_vector_type(4))) float f32x4;

__device__ __forceinline__ void gload_lds16(const void* g, void* l) {
    __builtin_amdgcn_global_load_lds(
        (const __attribute__((address_space(1))) unsigned int*)g,
        (__attribute__((address_space(3))) unsigned int*)l,
        16, 0, 0);
}

__device__ __forceinline__ u16 f2bf(float f) {  // RNE
    union { float f; unsigned int u; } v; v.f = f;
    unsigned int r = v.u + 0x7fffu + ((v.u >> 16) & 1u);
    return (u16)(r >> 16);
}

__device__ __forceinline__ float gelu_tanh(float x) {
    // 0.5x(1+tanh(0.79788456(x+0.044715x^3))); max |err| vs erf-GELU ~1e-3.
    const float z = 0.7978845608028654f * x * (1.0f + 0.044715f * x * x);
    const float t = __builtin_amdgcn_exp2f(2.885390081777927f * z);  // e^{2z}
    const float th = 1.0f - 2.0f * __builtin_amdgcn_rcpf(t + 1.0f);
    return 0.5f * x * (1.0f + th);
}

// ---------------------------------------------------------------------------
// 256x256 / BK=64 / 8-wave (2Mx4N) / 512-thread 8-phase pipelined GEMM
// (plain-HIP port of the HK-derived schedule; guide §5 "256² 8-phase").
// C = act(A @ Bt^T + bias). A: MxK bf16 k-contig, Bt: NxK bf16 k-contig.
//
// LDS (128 KiB, static): buf0.A [0,32K) buf0.B [32K,64K)
//                        buf1.A [64K,96K) buf1.B [96K,128K)
// Tile t (64 k-cols) lives in buf(t&1). Iteration it computes tiles t=2it
// (phases 1-4, quadrants Q0..Q3) and t+1 (phases 5-8) and stages:
//   ph1: buf1.A h0 <- tile t+1     ph5: buf0.A h0 <- tile t+2
//   ph2: buf1.A h1 <- tile t+1     ph6: buf0.A h1 <- tile t+2
//   ph3: buf0.B h0 <- tile t+2     ph7: buf1.B h0 <- tile t+3
//   ph4: buf0.B h1 <- tile t+2     ph8: buf1.B h1 <- tile t+3
// Every stage lands >=1 barrier after the last read of its region (B-halves
// are fully read by phase 2 of their tile, A-halves by phase 3). Counted
// s_waitcnt vmcnt(4) at phases 4/8 only (2 half-tiles = 4 global_load_lds
// per thread legitimately in flight); the peeled last iteration stages
// nothing for t+2/t+3 and must drain with vmcnt(0) at phase 4.
//
// Staging swizzle (session-verified, SQ_LDS_BANK_CONFLICT==0): LDS granule
// slot (r,s) holds global granule s^(r&7); fragment reads XOR-correct.
// ds_read base folds to base + mi*2048 immediates since (row&7)==(mrow&7).
//
// Epilogue: 4x 64-row fp32 LDS chunks, stride 256 f32 with 16B-granule XOR
// by (row&7) -> 2-way max on write and read; coalesced vector stores.
// SKIP_S: suppress stores of rows with (row0+row) % 2048 == 0.
// M%256==0, N%256==0, K%128==0.
// ---------------------------------------------------------------------------

#define STAGE(mb, hrow, kb, lbase)                                   \
    {                                                                \
        const char* _s = (mb) + (size_t)(hrow)*ldb + (kb);           \
        gload_lds16(_s + soff[0], smem + (lbase) + ldst[0]);         \
        gload_lds16(_s + soff[1], smem + (lbase) + ldst[1]);         \
    }
#define LOADA(bufo, mh)                                              \
    _Pragma("unroll") for (int ks = 0; ks < 2; ++ks) {               \
        const char* _p = smem + (bufo) + A0 + g2[ks] + (mh)*8192;    \
        _Pragma("unroll") for (int m = 0; m < 4; ++m)                \
            af[m][ks] = *(const bf16x8*)(_p + m * 2048);             \
    }
#define LOADB(bufo, nh)                                              \
    _Pragma("unroll") for (int ks = 0; ks < 2; ++ks) {               \
        const char* _p = smem + (bufo) + 32768 + B0 + g2[ks] + (nh)*4096; \
        _Pragma("unroll") for (int n = 0; n < 2; ++n)                \
            bf[(nh)*2 + n][ks] = *(const bf16x8*)(_p + n * 2048);    \
    }
#define QMFMA(MS, NS)                                                \
    __builtin_amdgcn_s_setprio(1);                                   \
    _Pragma("unroll") for (int ks = 0; ks < 2; ++ks)                 \
    _Pragma("unroll") for (int m = 0; m < 4; ++m)                    \
    _Pragma("unroll") for (int n = 0; n < 2; ++n)                    \
        acc[(MS) + m][(NS) + n] = __builtin_amdgcn_mfma_f32_16x16x32_bf16( \
            af[m][ks], bf[(NS) + n][ks], acc[(MS) + m][(NS) + n], 0, 0, 0); \
    __builtin_amdgcn_s_setprio(0);
#define BAR __builtin_amdgcn_s_barrier()
#define SB0 __builtin_amdgcn_sched_barrier(0)
#define LGKM0                                                        \
    {                                                                \
        asm volatile("s_waitcnt lgkmcnt(0)" ::: "memory");           \
        SB0;                                                         \
    }

template <int GELU, int OUT_BF16, int SKIP_S>
__global__ __launch_bounds__(512, 2) void gemm256(
    const u16* __restrict__ A, const u16* __restrict__ Bt,
    const float* __restrict__ bias, void* __restrict__ Cv,
    int N, int K, int row0) {
    __shared__ __align__(16) char smem[131072];

    const int tid = threadIdx.x, lane = tid & 63, wave = tid >> 6;
    const int wr = wave >> 2, wc = wave & 3;        // 2M x 4N wave grid
    const int mrow = lane & 15, half = lane >> 4;

    const size_t ldb = (size_t)K * 2;  // row stride bytes
    const char* Ab = (const char*)A + (size_t)blockIdx.x * 256 * ldb;
    const char* Bb = (const char*)Bt + (size_t)blockIdx.y * 256 * ldb;

    // Staging: half-tile = 128 rows x 8 granules(16B); thread does granule
    // L=tid and L=tid+512. r=L>>3, s=L&7; source pre-swizzled s^(r&7).
    size_t soff[2];
    int ldst[2];
#pragma unroll
    for (int i = 0; i < 2; ++i) {
        const int L = tid + 512 * i, r = L >> 3, s = L & 7;
        soff[i] = (size_t)r * ldb + (size_t)((s ^ (r & 7)) << 4);
        ldst[i] = L << 4;
    }

    // Fragment ds_read bases. Row = wr*128 + mi*16 + mrow (A) — since the
    // mi*16 term is 0 mod 8, the granule swizzle depends only on mrow&7:
    // g2[ks] = ((ks*4+half) ^ (mrow&7))<<4; mi folds into the b128 offset.
    const int A0 = (wr * 128 + mrow) * 128;
    const int B0 = (wc * 64 + mrow) * 128;
    int g2[2];
#pragma unroll
    for (int ks = 0; ks < 2; ++ks) g2[ks] = ((ks * 4 + half) ^ (mrow & 7)) << 4;

    f32x4 acc[8][4];
#pragma unroll
    for (int i = 0; i < 8; ++i)
#pragma unroll
        for (int j = 0; j < 4; ++j) acc[i][j] = f32x4{0.f, 0.f, 0.f, 0.f};

    bf16x8 af[4][2], bf[4][2];

    // Prologue: tile0 -> buf0 (A h0,h1, B h0,h1); tile1 B -> buf1.B.
    STAGE(Ab, 0, 0, 0)
    STAGE(Ab, 128, 0, 16384)
    STAGE(Bb, 0, 0, 32768)
    STAGE(Bb, 128, 0, 49152)
    STAGE(Bb, 0, 128, 98304)
    STAGE(Bb, 128, 0 + 128, 114688)
    asm volatile("s_waitcnt vmcnt(4)" ::: "memory");  // buf0 landed
    SB0;
    BAR;
    SB0;

    const int niter = K >> 7;  // 2 K-tiles (128 k) per iteration
    for (int it = 0; it < niter; ++it) {
        const bool last = (it == niter - 1);
        const size_t kb1 = (size_t)(2 * it + 1) << 7;  // byte k-off tile t+1
        const size_t kb2 = kb1 + 128, kb3 = kb1 + 256;
        // ph1: Q0 of tile t
        LOADA(0, 0)
        LOADB(0, 0)
        STAGE(Ab, 0, kb1, 65536)
        BAR;
        LGKM0
        QMFMA(0, 0)
        BAR;
        // ph2: Q1
        LOADB(0, 1)
        STAGE(Ab, 128, kb1, 81920)
        BAR;
        LGKM0
        QMFMA(0, 2)
        BAR;
        // ph3: Q2
        LOADA(0, 1)
        if (!last) STAGE(Bb, 0, kb2, 32768)
        BAR;
        LGKM0
        QMFMA(4, 0)
        BAR;
        // ph4: Q3 + W4 gate (tile t+1 must be fully resident after this)
        if (!last) STAGE(Bb, 128, kb2, 49152)
        BAR;
        QMFMA(4, 2)
        if (last) {
            asm volatile("s_waitcnt vmcnt(0)" ::: "memory");
        } else {
            asm volatile("s_waitcnt vmcnt(4)" ::: "memory");
        }
        SB0;
        BAR;
        SB0;
        // ph5: Q0 of tile t+1
        LOADA(65536, 0)
        LOADB(65536, 0)
        if (!last) STAGE(Ab, 0, kb2, 0)
        BAR;
        LGKM0
        QMFMA(0, 0)
        BAR;
        // ph6: Q1
        LOADB(65536, 1)
        if (!last) STAGE(Ab, 128, kb2, 16384)
        BAR;
        LGKM0
        QMFMA(0, 2)
        BAR;
        // ph7: Q2
        LOADA(65536, 1)
        if (!last) STAGE(Bb, 0, kb3, 98304)
        BAR;
        LGKM0
        QMFMA(4, 0)
        BAR;
        // ph8: Q3 + W8 gate (tile t+2 must be fully resident after this)
        if (!last) STAGE(Bb, 128, kb3, 114688)
        BAR;
        QMFMA(4, 2)
        if (!last) asm volatile("s_waitcnt vmcnt(4)" ::: "memory");
        SB0;
        BAR;
        SB0;
    }

    // Epilogue. C/D layout (m89): row = wr*128 + mi*16 + half*4 + r,
    // col = wc*64 + ni*16 + mrow. 4 chunks of 64 rows; fp32 LDS stride 256
    // with 16B-granule XOR by (row&7): write 2-way max, read spreads the 8
    // per-row lanes over 8 distinct bank-quads (ideal for b128).
    const int growbase = blockIdx.x * 256, gcolbase = blockIdx.y * 256;
    float* Ct = (float*)smem;
    const int rr = tid >> 3, gb = tid & 7, r7 = rr & 7;
#pragma unroll
    for (int c = 0; c < 4; ++c) {
        __syncthreads();  // prior chunk reads (or K-loop) done
        if (wr == (c >> 1)) {
#pragma unroll
            for (int dm = 0; dm < 4; ++dm) {
                const int mi = (c & 1) * 4 + dm;
#pragma unroll
                for (int ni = 0; ni < 4; ++ni) {
                    const int col = wc * 64 + ni * 16 + mrow;
                    const float bv = bias[gcolbase + col];
#pragma unroll
                    for (int r = 0; r < 4; ++r) {
                        const int rloc = dm * 16 + half * 4 + r;
                        float v = acc[mi][ni][r] + bv;
                        if (GELU) v = gelu_tanh(v);
                        Ct[rloc * 256 +
                           ((((col >> 2) ^ (rloc & 7)) << 2) | (col & 3))] = v;
                    }
                }
            }
        }
        __syncthreads();  // chunk written
        const int grow = growbase + 64 * c + rr;
        if (!(SKIP_S && (((row0 + grow) & 2047) == 0))) {
            // thread covers cols 4*gb + 32*j, j=0..7 (slot (gb^r7)+8j)
            f32x4 v[8];
#pragma unroll
            for (int j = 0; j < 8; ++j)
                v[j] = *(const f32x4*)(Ct + rr * 256 +
                                       (((gb ^ r7) + 8 * j) << 2));
            if (OUT_BF16) {
                u16* p = (u16*)Cv + (size_t)grow * N + gcolbase + gb * 4;
#pragma unroll
                for (int j = 0; j < 8; ++j) {
                    u16x4 o;
#pragma unroll
                    for (int e = 0; e < 4; ++e) o[e] = f2bf(v[j][e]);
                    *(u16x4*)(p + 32 * j) = o;
                }
            } else {
                float* p = (float*)Cv + (size_t)grow * N + gcolbase + gb * 4;
#pragma unroll
                for (int j = 0; j < 8; ++j) *(f32x4*)(p + 32 * j) = v[j];
            }
        }
    }
}

__device__ __forceinline__ void tcvt_block(const float* __restrict__ src,
                                           u16* __restrict__ dst, int R, int C,
                                           int bx, int by, int x, int y,
                                           u16 (*t)[33]) {
    for (int i = 0; i < 32; i += 8)
        t[y + i][x] = f2bf(src[(size_t)(by + y + i) * C + (bx + x)]);
    __syncthreads();
    for (int i = 0; i < 32; i += 8)
        dst[(size_t)(bx + y + i) * R + (by + x)] = t[x][y + i];
}

// One fused prep dispatch (block-uniform branch on blockIdx ranges):
//   [0,2048)    transpose+cvt W1 (1024x2048 fp32 -> 2048x1024 bf16)
//   [2048,4096) transpose+cvt W2 (2048x1024 fp32 -> 1024x2048 bf16)
//   [4096,4104) out[b,0,:] = X[b,0,:]   (fp32 first-token rows; GEMM2 masks
//               these rows, so prep-before-GEMM2 ordering is irrelevant)
//   [4104,8200) grid-stride cvt X fp32 -> bf16 (16.78M elems, 4 passes)
__global__ void prep(const float* __restrict__ X, const float* __restrict__ W1,
                     const float* __restrict__ W2, u16* __restrict__ Xb,
                     u16* __restrict__ W1T, u16* __restrict__ W2T,
                     float* __restrict__ out, long long nX) {
    __shared__ u16 t[32][33];
    const int b = blockIdx.x, tid = threadIdx.x;
    const int x = tid & 31, y = tid >> 5;
    if (b < 2048) {            // W1: R=1024 rows, C=2048 cols; 64x32 blocks
        tcvt_block(W1, W1T, 1024, 2048, (b & 63) * 32, (b >> 6) * 32, x, y, t);
    } else if (b < 4096) {     // W2: R=2048, C=1024; 32x64 blocks
        const int bi = b - 2048;
        tcvt_block(W2, W2T, 2048, 1024, (bi & 31) * 32, (bi >> 5) * 32, x, y, t);
    } else if (b < 4104) {     // first-token copy, D=1024 floats = 256*float4
        const size_t base = (size_t)(b - 4096) * 2048 * 1024;
        *(float4*)(out + base + tid * 4) = *(const float4*)(X + base + tid * 4);
    } else {                   // cvt X
        const long long stride = (long long)4096 * 256 * 4;
        for (long long i = ((long long)(b - 4104) * 256 + tid) * 4; i < nX;
             i += stride) {
            const float4 v = *(const float4*)(X + i);
            ushort4 o;
            o.x = f2bf(v.x); o.y = f2bf(v.y); o.z = f2bf(v.z); o.w = f2bf(v.w);
            *(ushort4*)(Xb + i) = o;
        }
    }
}

extern "C" void kernel_launch(void* const* d_in, const int* in_sizes, int n_in,
                              void* d_out, int out_size, void* d_ws, size_t ws_size,
                              hipStream_t stream) {
    const float* X  = (const float*)d_in[0];  // [B,S,D] fp32
    const float* W1 = (const float*)d_in[1];  // [D,H]
    const float* b1 = (const float*)d_in[2];  // [H]
    const float* W2 = (const float*)d_in[3];  // [H,D]
    const float* b2 = (const float*)d_in[4];  // [D]
    float* out = (float*)d_out;

    const int B = 8, S = 2048, D = 1024, H = 2048;
    const int M = B * S;  // 16384

    // ws: W1T bf16 HxD (4MB) | W2T bf16 DxH (4MB) | Xb bf16 MxD (32MB) |
    //     Hb bf16 CMxH
    u16* W1T = (u16*)d_ws;
    u16* W2T = W1T + (size_t)H * D;
    u16* Xb  = W2T + (size_t)D * H;
    u16* Hb  = Xb + (size_t)M * D;
    const size_t wfixed = (size_t)H * D * 2 * 2 + (size_t)M * D * 2;  // 40 MB
    size_t avail_rows = (ws_size > wfixed) ? (ws_size - wfixed) / ((size_t)H * 2) : 0;
    int CM = (int)((avail_rows / 256) * 256);
    if (CM > M) CM = M;
    if (CM < 256) CM = 256;

    prep<<<dim3(8200), dim3(256), 0, stream>>>(
        X, W1, W2, Xb, W1T, W2T, out, (long long)M * D);

    for (int m0 = 0; m0 < M; m0 += CM) {
        const int rows = (M - m0 < CM) ? (M - m0) : CM;
        dim3 g1(rows / 256, H / 256);
        gemm256<1, 1, 0><<<g1, dim3(512), 0, stream>>>(
            Xb + (size_t)m0 * D, W1T, b1, Hb, H, D, m0);
        dim3 g2(rows / 256, D / 256);
        gemm256<0, 0, 1><<<g2, dim3(512), 0, stream>>>(
            Hb, W2T, b2, out + (size_t)m0 * D, D, H, m0);
    }
}